// Round 5
// baseline (4452.754 us; speedup 1.0000x reference)
//
#include <hip/hip_runtime.h>
#include <hip/hip_fp16.h>

// Bidirectional GRU (B=64,S=1024,E=H=256) + FC/ReLU head.
// k_gx: gx = x@W_ih^T (+biases) both dirs, f16 MFMA, f16 consumer-ordered out.
// k_rec: persistent 8 WGs (2 dir x 4 bslice) x 1024 thr (16 waves, 4/SIMD).
//        Wave owns 16 cols/gate: wf[3][8] = 96 VGPRs (no AGPR pressure).
//        h in LDS in MFMA-A-frag order (linear conflict-free ds_read_b128),
//        ping-pong tiles, ONE __syncthreads/step, gx prefetched 1 step ahead,
//        out-stores deferred 1 step, setprio(1) around MFMA cluster.
// k_fc: relu(concat @ W_fc^T + b) in place over f16 h written into d_out.
// ws: CT*196608 + 131072 B; CT=1024 fits (round-3 evidence ws >= 201.5MB).

typedef _Float16 f16x8 __attribute__((ext_vector_type(8)));
typedef _Float16 f16x4 __attribute__((ext_vector_type(4)));
typedef float    f32x4 __attribute__((ext_vector_type(4)));

#define MFMA(a,b,c) __builtin_amdgcn_mfma_f32_16x16x32_f16((a),(b),(c),0,0,0)
#define SWZ(r,c)  ((((r)*512)  + (c)) ^ (((r)&7)<<4))
#define SWZ2(r,c) ((((r)*1024) + (c)) ^ (((r)&7)<<4))

__device__ inline f16x8 pack8(float4 a, float4 b){
  f16x8 h;
  h[0]=(_Float16)a.x; h[1]=(_Float16)a.y; h[2]=(_Float16)a.z; h[3]=(_Float16)a.w;
  h[4]=(_Float16)b.x; h[5]=(_Float16)b.y; h[6]=(_Float16)b.z; h[7]=(_Float16)b.w;
  return h;
}
__device__ inline float fsigm(float x){
  return __builtin_amdgcn_rcpf(1.f + __expf(-x));
}
__device__ inline float ftanh(float x){
  float e = __expf(2.f*x);                   // +inf -> 1, 0 -> -1
  return 1.f - 2.f*__builtin_amdgcn_rcpf(e + 1.f);
}

// ---------------- gx: gx = x @ W_ih^T + b_ih (+ b_hh for r,z) ----------------
__global__ __launch_bounds__(256) void k_gx(
    const float* __restrict__ X,
    const float* __restrict__ Wf, const float* __restrict__ bihf, const float* __restrict__ bhhf,
    const float* __restrict__ Wb, const float* __restrict__ bihb, const float* __restrict__ bhhb,
    _Float16* __restrict__ gxc, int CT, int sbase)
{
  const int tc = blockIdx.x, dir = blockIdx.y;
  const int p = sbase + tc;
  const int t = dir ? (1023 - p) : p;
  const float* __restrict__ Wp = dir ? Wb : Wf;
  const float* __restrict__ bi = dir ? bihb : bihf;
  const float* __restrict__ bh = dir ? bhhb : bhhf;
  __shared__ _Float16 As[64*256];            // 32KB
  __shared__ _Float16 Bs[64*256];            // 32KB
  const int tid = threadIdx.x;
  #pragma unroll
  for (int i = 0; i < 8; ++i) {              // stage A: rows = batch b, fixed t
    int c = tid + i*256, r = c >> 5, cc = c & 31;
    const float4* s4 = (const float4*)(X + ((size_t)r*1024 + t)*256 + cc*8);
    *(f16x8*)((char*)As + SWZ(r, cc*16)) = pack8(s4[0], s4[1]);
  }
  const int w = tid >> 6, l = tid & 63, lr = l & 15, g = l >> 4;
  const size_t obase = (((size_t)dir*CT + tc)*4 + w) * (size_t)12288;  // f16 units
  #pragma unroll 1
  for (int nt = 0; nt < 12; ++nt) {
    __syncthreads();
    #pragma unroll
    for (int i = 0; i < 8; ++i) {            // stage B: W rows nt*64..+64
      int c = tid + i*256, r = c >> 5, cc = c & 31;
      const float4* s4 = (const float4*)(Wp + (size_t)(nt*64 + r)*256 + cc*8);
      *(f16x8*)((char*)Bs + SWZ(r, cc*16)) = pack8(s4[0], s4[1]);
    }
    __syncthreads();
    f32x4 acc[4];
    #pragma unroll
    for (int ct = 0; ct < 4; ++ct) acc[ct] = (f32x4){0.f,0.f,0.f,0.f};
    #pragma unroll
    for (int kk = 0; kk < 8; ++kk) {
      f16x8 af = *(const f16x8*)((const char*)As + SWZ(w*16 + lr, kk*64 + g*16));
      #pragma unroll
      for (int ct = 0; ct < 4; ++ct) {
        f16x8 bfr = *(const f16x8*)((const char*)Bs + SWZ(ct*16 + lr, kk*64 + g*16));
        acc[ct] = MFMA(af, bfr, acc[ct]);
      }
    }
    #pragma unroll
    for (int ct = 0; ct < 4; ++ct) {         // consumer layout [3][1024 tid][4]
      const int col = nt*64 + ct*16 + lr;
      const float bv = bi[col] + (col < 512 ? bh[col] : 0.f);
      const int gate = col >> 8, j = col & 255;
      const int tid2 = (j>>4)*64 + g*16 + (j&15);
      f16x4 v;
      #pragma unroll
      for (int q = 0; q < 4; ++q) v[q] = (_Float16)(acc[ct][q] + bv);
      *(f16x4*)(gxc + obase + gate*4096 + tid2*4) = v;
    }
  }
}

// ---------------- GRU recurrence ----------------
// 1024 thr = 16 waves; wave w owns col j = w*16 + lr of each gate (3 col-tiles).
// h tile in A-frag order: h[r][k] at byte (k>>5)*1024 + (((k>>3)&3)*16 + r)*16 + (k&7)*2;
// af read for kk = ds_read_b128 at l*16 + kk*1024 (linear, conflict-free).
// Thread (w,l) produces h[g*4+q][w*16+lr], q=0..3.
__global__ __launch_bounds__(1024, 4) void k_rec(
    const float* __restrict__ Whh_f, const float* __restrict__ bhh_f,
    const float* __restrict__ Whh_b, const float* __restrict__ bhh_b,
    const _Float16* __restrict__ gxc, float* __restrict__ wsh,
    _Float16* __restrict__ out16, float* __restrict__ hidden,
    int CT, int sbase)
{
  const int dir = blockIdx.x & 1;
  const int bsl = blockIdx.x >> 1;
  const int bbase = bsl * 16;
  const float* __restrict__ Whh = dir ? Whh_b : Whh_f;
  const float* __restrict__ bhh = dir ? bhh_b : bhh_f;
  const int tid = threadIdx.x, w = tid >> 6, l = tid & 63;
  const int lr = l & 15, g = l >> 4;
  const int j0 = w * 16;
  f16x8 wf[3][8];                            // B-frag: W[col=ct*256+j0+lr][k=kk*32+g*8+i]
  #pragma unroll
  for (int ct = 0; ct < 3; ++ct) {
    const int colg = ct*256 + j0 + lr;
    #pragma unroll
    for (int kk = 0; kk < 8; ++kk) {
      const float4* s4 = (const float4*)(Whh + (size_t)colg*256 + kk*32 + g*8);
      wf[ct][kk] = pack8(s4[0], s4[1]);
    }
  }
  const float bn = bhh[512 + j0 + lr];       // n-gate bhh (inside r*(.))
  __shared__ _Float16 hs[2][4096];           // ping-pong A-frag-ordered h tiles (16KB)
  char* const afp = (char*)hs + l*16;
  char* const hwp = (char*)hs + (w>>1)*1024 + ((w&1)*2 + (lr>>3))*256 + g*64 + (lr&7)*2;
  float hold[4];
  if (sbase == 0) {
    if (tid < 512) *(int4*)((char*)hs + tid*16) = make_int4(0,0,0,0);
    #pragma unroll
    for (int q = 0; q < 4; ++q) hold[q] = 0.f;
  } else {                                   // restore h from previous chunk
    if (tid < 512) {
      const int r = tid >> 5, kq = tid & 31;
      const float4* s4 = (const float4*)(wsh + ((size_t)(dir*64 + bbase + r))*256 + kq*8);
      *(f16x8*)((char*)hs + (kq>>2)*1024 + (((kq&3)*16) + r)*16) = pack8(s4[0], s4[1]);
    }
    #pragma unroll
    for (int q = 0; q < 4; ++q)
      hold[q] = wsh[((size_t)(dir*64 + bbase + g*4 + q))*256 + j0 + lr];
  }
  __syncthreads();

  const int t0 = dir ? (1023 - sbase) : sbase;
  char* optr = (char*)out16 + ((size_t)t0*64 + bbase + g*4)*1024
             + (size_t)(dir*256 + j0 + lr)*2;
  const ptrdiff_t ostep = dir ? -(ptrdiff_t)65536 : (ptrdiff_t)65536;
  const _Float16* gp = gxc + ((size_t)(dir*CT)*4 + bsl)*12288 + (size_t)tid*4;
  const ptrdiff_t gstep = 49152;             // 4*12288 f16 per step
  // prologue prefetch (sc=0)
  f16x4 ga0 = *(const f16x4*)(gp);
  f16x4 ga1 = *(const f16x4*)(gp + 4096);
  f16x4 ga2 = *(const f16x4*)(gp + 8192);
  gp += gstep;
  f16x4 gb0, gb1, gb2;
  f16x4 houts;                               // h(s-1) carried for deferred out-store
  bool sten = false;

  // NOTE: last prefetch overruns gxc by < 96KB+8KB, landing inside the 128KB
  // wsh slab -> in-bounds garbage, never consumed.
#define REC_STEP(RB, GC0,GC1,GC2, GN0,GN1,GN2)                                     \
  {                                                                                \
    GN0 = *(const f16x4*)(gp);                                                     \
    GN1 = *(const f16x4*)(gp + 4096);                                              \
    GN2 = *(const f16x4*)(gp + 8192);                                              \
    gp += gstep;                                                                   \
    if (sten) {                              /* store h(s-1): full step to drain */\
      _Pragma("unroll")                                                            \
      for (int q = 0; q < 4; ++q)                                                  \
        *(_Float16*)(optr + q*1024) = houts[q];                                    \
      optr += ostep;                                                               \
    }                                                                              \
    sten = true;                                                                   \
    f32x4 acc0 = (f32x4){0.f,0.f,0.f,0.f};                                         \
    f32x4 acc1 = (f32x4){0.f,0.f,0.f,0.f};                                         \
    f32x4 acc2 = (f32x4){bn,bn,bn,bn};                                             \
    __builtin_amdgcn_s_setprio(1);                                                 \
    _Pragma("unroll")                                                              \
    for (int kk = 0; kk < 8; ++kk) {                                               \
      f16x8 af = *(const f16x8*)(afp + (RB)*8192 + kk*1024);                       \
      acc0 = MFMA(af, wf[0][kk], acc0);                                            \
      acc1 = MFMA(af, wf[1][kk], acc1);                                            \
      acc2 = MFMA(af, wf[2][kk], acc2);                                            \
    }                                                                              \
    __builtin_amdgcn_s_setprio(0);                                                 \
    _Pragma("unroll")                                                              \
    for (int q = 0; q < 4; ++q) {                                                  \
      const float rg = fsigm((float)GC0[q] + acc0[q]);                             \
      const float zg = fsigm((float)GC1[q] + acc1[q]);                             \
      const float ng = ftanh((float)GC2[q] + rg*acc2[q]);                          \
      const float h = ng + zg*(hold[q] - ng);                                      \
      hold[q] = h;                                                                 \
      const _Float16 hf = (_Float16)h;                                             \
      houts[q] = hf;                                                               \
      *(_Float16*)(hwp + ((RB)^1)*8192 + q*16) = hf;                               \
    }                                                                              \
    __syncthreads();                                                               \
  }

  #pragma unroll 1
  for (int sc = 0; sc < CT; sc += 2) {
    REC_STEP(0, ga0,ga1,ga2, gb0,gb1,gb2)
    REC_STEP(1, gb0,gb1,gb2, ga0,ga1,ga2)
  }
#undef REC_STEP

  // store h(CT-1)
  #pragma unroll
  for (int q = 0; q < 4; ++q)
    *(_Float16*)(optr + q*1024) = houts[q];

  if (sbase + CT == 1024) {                  // final h -> hidden output
    #pragma unroll
    for (int q = 0; q < 4; ++q)
      hidden[((size_t)(dir*64 + bbase + g*4 + q))*256 + j0 + lr] = hold[q];
  } else {                                   // persist h for next chunk
    #pragma unroll
    for (int q = 0; q < 4; ++q)
      wsh[((size_t)(dir*64 + bbase + g*4 + q))*256 + j0 + lr] = hold[q];
  }
}

// ---------------- FC in place: relu(concat_f16 @ W_fc^T + b) -> f32 ----------------
__global__ __launch_bounds__(256) void k_fc(
    const _Float16* __restrict__ h16, const float* __restrict__ Wfc,
    const float* __restrict__ bfc, float* __restrict__ out)
{
  const int mt = blockIdx.x;
  __shared__ _Float16 As[64*512];            // 64KB
  const int tid = threadIdx.x, w = tid >> 6, l = tid & 63;
  const int lr = l & 15, g = l >> 4;
  #pragma unroll
  for (int i = 0; i < 16; ++i) {
    int c = tid + i*256, r = c >> 6, cc = c & 63;
    *(int4*)((char*)As + SWZ2(r, cc*16)) =
        *(const int4*)((const char*)h16 + ((size_t)mt*64 + r)*1024 + cc*16);
  }
  __syncthreads();                           // all h16 reads drained before any store
  #pragma unroll 1
  for (int nt = 0; nt < 4; ++nt) {
    f32x4 acc[4];
    #pragma unroll
    for (int ct = 0; ct < 4; ++ct) acc[ct] = (f32x4){0.f,0.f,0.f,0.f};
    #pragma unroll 2
    for (int kk = 0; kk < 16; ++kk) {
      f16x8 af = *(const f16x8*)((const char*)As + SWZ2(w*16 + lr, kk*64 + g*16));
      #pragma unroll
      for (int ct = 0; ct < 4; ++ct) {
        const float4* s4 = (const float4*)(Wfc + (size_t)(nt*64 + ct*16 + lr)*512 + kk*32 + g*8);
        acc[ct] = MFMA(af, pack8(s4[0], s4[1]), acc[ct]);
      }
    }
    #pragma unroll
    for (int ct = 0; ct < 4; ++ct) {
      const int col = nt*64 + ct*16 + lr;
      const float bv = bfc[col];
      #pragma unroll
      for (int q = 0; q < 4; ++q) {
        const int row = w*16 + g*4 + q;
        out[((size_t)mt*64 + row)*256 + col] = fmaxf(acc[ct][q] + bv, 0.f);
      }
    }
  }
}

extern "C" void kernel_launch(void* const* d_in, const int* in_sizes, int n_in,
                              void* d_out, int out_size, void* d_ws, size_t ws_size,
                              hipStream_t stream) {
  const float* X      = (const float*)d_in[0];
  const float* W_ih_f = (const float*)d_in[1];
  const float* W_hh_f = (const float*)d_in[2];
  const float* b_ih_f = (const float*)d_in[3];
  const float* b_hh_f = (const float*)d_in[4];
  const float* W_ih_b = (const float*)d_in[5];
  const float* W_hh_b = (const float*)d_in[6];
  const float* b_ih_b = (const float*)d_in[7];
  const float* b_hh_b = (const float*)d_in[8];
  const float* W_fc   = (const float*)d_in[9];
  const float* b_fc   = (const float*)d_in[10];

  // CT=1024 (one shot) when ws allows; round-3 evidence: ws_size >= 201.5MB.
  int CT = 1024;
  while (CT > 8 && ((size_t)CT*196608 + 131072) > ws_size) CT >>= 1;
  _Float16* gxc = (_Float16*)d_ws;                     // [2][CT][4][3][1024][4] f16
  float*    wsh = (float*)((char*)d_ws + (size_t)CT*196608);  // [2][64][256] f32

  _Float16* h16   = (_Float16*)d_out;                  // [1024][64][512] f16 (in-place)
  float*    out   = (float*)d_out;                     // [1024][64][256] f32
  float*    hidden= (float*)d_out + (size_t)1024*64*256;

  const int NC = 1024 / CT;
  for (int c = 0; c < NC; ++c) {
    k_gx<<<dim3(CT, 2), dim3(256), 0, stream>>>(X, W_ih_f, b_ih_f, b_hh_f,
                                                W_ih_b, b_ih_b, b_hh_b, gxc, CT, c*CT);
    k_rec<<<dim3(8), dim3(1024), 0, stream>>>(W_hh_f, b_hh_f, W_hh_b, b_hh_b,
                                              gxc, wsh, h16, hidden, CT, c*CT);
  }
  k_fc<<<dim3(1024), dim3(256), 0, stream>>>(h16, W_fc, b_fc, out);
}

// Round 6
// 4332.520 us; speedup vs baseline: 1.0278x; 1.0278x over previous
//
#include <hip/hip_runtime.h>
#include <hip/hip_fp16.h>

// Bidirectional GRU (B=64,S=1024,E=H=256) + FC/ReLU head — chunked pipeline.
// k_gx: gx = x@W_ih^T (+biases), f16 MFMA; output PRE-SCALED by -log2e (r,z) /
//       +2log2e (n) so k_rec gates use exp2 directly; consumer layout
//       [dir][t][bsl][gate][tid512][8] -> 16B-aligned f16x8 loads.
// k_rec: persistent 8 WGs (2 dir x 4 bslice) x 512 thr (8 waves, 2/SIMD,
//        launch_bounds(512,2) -> 128 arch VGPR). W_hh f16 frags reg-resident,
//        pre-scaled. h in LDS in MFMA-A-frag order (linear ds_read_b128).
//        Ping-pong h tiles; raw s_barrier + lgkm-only waitcnt (NO vmcnt drain);
//        gx prefetch 1 step ahead; out16 stores deferred 1 step;
//        MFMA grouped acc-major {r0,z0,n0,r1,z1,n1} + setprio(1).
// k_fc: relu(concat @ W_fc^T + b) in place over f16 h written into d_out.

typedef _Float16 f16x8 __attribute__((ext_vector_type(8)));
typedef _Float16 f16x4 __attribute__((ext_vector_type(4)));
typedef float    f32x4 __attribute__((ext_vector_type(4)));

#define MFMA(a,b,c) __builtin_amdgcn_mfma_f32_16x16x32_f16((a),(b),(c),0,0,0)
#define SWZ(r,c)  ((((r)*512)  + (c)) ^ (((r)&7)<<4))
#define SWZ2(r,c) ((((r)*1024) + (c)) ^ (((r)&7)<<4))

#define NLOG2E (-1.442695041f)
#define P2LOG2E (2.885390082f)

__device__ inline f16x8 pack8(float4 a, float4 b){
  f16x8 h;
  h[0]=(_Float16)a.x; h[1]=(_Float16)a.y; h[2]=(_Float16)a.z; h[3]=(_Float16)a.w;
  h[4]=(_Float16)b.x; h[5]=(_Float16)b.y; h[6]=(_Float16)b.z; h[7]=(_Float16)b.w;
  return h;
}
__device__ inline f16x8 pack8s(float4 a, float4 b, float s){
  f16x8 h;
  h[0]=(_Float16)(a.x*s); h[1]=(_Float16)(a.y*s); h[2]=(_Float16)(a.z*s); h[3]=(_Float16)(a.w*s);
  h[4]=(_Float16)(b.x*s); h[5]=(_Float16)(b.y*s); h[6]=(_Float16)(b.z*s); h[7]=(_Float16)(b.w*s);
  return h;
}

// ---------------- gx: gx = scale * (x @ W_ih^T + b_ih (+ b_hh for r,z)) ----------------
__global__ __launch_bounds__(256) void k_gx(
    const float* __restrict__ X,
    const float* __restrict__ Wf, const float* __restrict__ bihf, const float* __restrict__ bhhf,
    const float* __restrict__ Wb, const float* __restrict__ bihb, const float* __restrict__ bhhb,
    _Float16* __restrict__ gxc, int CT, int sbase)
{
  const int tc = blockIdx.x, dir = blockIdx.y;
  const int p = sbase + tc;
  const int t = dir ? (1023 - p) : p;
  const float* __restrict__ Wp = dir ? Wb : Wf;
  const float* __restrict__ bi = dir ? bihb : bihf;
  const float* __restrict__ bh = dir ? bhhb : bhhf;
  __shared__ _Float16 As[64*256];            // 32KB
  __shared__ _Float16 Bs[64*256];            // 32KB
  const int tid = threadIdx.x;
  #pragma unroll
  for (int i = 0; i < 8; ++i) {              // stage A: rows = batch b, fixed t
    int c = tid + i*256, r = c >> 5, cc = c & 31;
    const float4* s4 = (const float4*)(X + ((size_t)r*1024 + t)*256 + cc*8);
    *(f16x8*)((char*)As + SWZ(r, cc*16)) = pack8(s4[0], s4[1]);
  }
  const int w = tid >> 6, l = tid & 63, lr = l & 15, g = l >> 4;
  const size_t obase = (((size_t)dir*CT + tc)*4 + w) * (size_t)12288;  // f16 units
  #pragma unroll 1
  for (int nt = 0; nt < 12; ++nt) {
    __syncthreads();
    #pragma unroll
    for (int i = 0; i < 8; ++i) {            // stage B: W rows nt*64..+64
      int c = tid + i*256, r = c >> 5, cc = c & 31;
      const float4* s4 = (const float4*)(Wp + (size_t)(nt*64 + r)*256 + cc*8);
      *(f16x8*)((char*)Bs + SWZ(r, cc*16)) = pack8(s4[0], s4[1]);
    }
    __syncthreads();
    f32x4 acc[4];
    #pragma unroll
    for (int ct = 0; ct < 4; ++ct) acc[ct] = (f32x4){0.f,0.f,0.f,0.f};
    #pragma unroll
    for (int kk = 0; kk < 8; ++kk) {
      f16x8 af = *(const f16x8*)((const char*)As + SWZ(w*16 + lr, kk*64 + g*16));
      #pragma unroll
      for (int ct = 0; ct < 4; ++ct) {
        f16x8 bfr = *(const f16x8*)((const char*)Bs + SWZ(ct*16 + lr, kk*64 + g*16));
        acc[ct] = MFMA(af, bfr, acc[ct]);
      }
    }
    #pragma unroll
    for (int ct = 0; ct < 4; ++ct) {         // consumer layout [gate][tid512][8]
      const int col = nt*64 + ct*16 + lr;
      const int gate = col >> 8;
      const float sc = (gate == 2) ? P2LOG2E : NLOG2E;
      const float bv = bi[col] + (gate < 2 ? bh[col] : 0.f);
      const int j = col & 255;
      const int tid2 = (j>>5)*64 + g*16 + (j&15);
      const int off = ((j>>4)&1)*4;          // jt*4
      f16x4 v;
      #pragma unroll
      for (int q = 0; q < 4; ++q) v[q] = (_Float16)((acc[ct][q] + bv)*sc);
      *(f16x4*)(gxc + obase + gate*4096 + tid2*8 + off) = v;
    }
  }
}

// ---------------- GRU recurrence, one chunk of CT steps ----------------
// h tile in A-frag order: h[r][k] at byte (k>>5)*1024 + ((k>>3)&3)*256 + r*16 + (k&7)*2;
// af read for kk = ds_read_b128 at l*16 + kk*1024 (linear, conflict-free).
// Thread (w,l) produces h[g*4+q][w*32+jt*16+lr].
// Gates (pre-scaled): r = rcp(1+exp2(xr'+hr')), z likewise,
//                     n = 1 - 2*rcp(1+exp2(xn' + r*hn')), h = n + z*(h_old-n).
__global__ __launch_bounds__(512, 2) void k_rec(
    const float* __restrict__ Whh_f, const float* __restrict__ bhh_f,
    const float* __restrict__ Whh_b, const float* __restrict__ bhh_b,
    const _Float16* __restrict__ gxc, float* __restrict__ wsh,
    _Float16* __restrict__ out16, float* __restrict__ hidden,
    int CT, int sbase)
{
  const int dir = blockIdx.x & 1;
  const int bsl = blockIdx.x >> 1;
  const int bbase = bsl * 16;
  const float* __restrict__ Whh = dir ? Whh_b : Whh_f;
  const float* __restrict__ bhh = dir ? bhh_b : bhh_f;
  const int tid = threadIdx.x, w = tid >> 6, l = tid & 63;
  const int lr = l & 15, g = l >> 4;
  const int j0 = w * 32;
  f16x8 wf[6][8];                            // B-frag: W[col][k=kk*32+g*8+i], pre-scaled
  #pragma unroll
  for (int ct = 0; ct < 6; ++ct) {
    const int colg = (ct>>1)*256 + j0 + (ct&1)*16 + lr;
    const float scl = (ct < 4) ? NLOG2E : P2LOG2E;
    #pragma unroll
    for (int kk = 0; kk < 8; ++kk) {
      const float4* s4 = (const float4*)(Whh + (size_t)colg*256 + kk*32 + g*8);
      wf[ct][kk] = pack8s(s4[0], s4[1], scl);
    }
  }
  const float bn0 = P2LOG2E * bhh[512 + j0 + lr];        // n-gate bhh, pre-scaled
  const float bn1 = P2LOG2E * bhh[512 + j0 + 16 + lr];
  __shared__ _Float16 hs[2][4096];           // ping-pong A-frag-ordered h tiles (16KB)
  char* const afp = (char*)hs + l*16;
  char* const hwp = (char*)hs + w*1024 + (lr>>3)*256 + g*64 + (lr&7)*2;
  float hold[2][4];
  if (sbase == 0) {
    *(int4*)((char*)hs + tid*16) = make_int4(0,0,0,0);   // hs[0] := 0 (8KB exact)
    #pragma unroll
    for (int jt = 0; jt < 2; ++jt)
      #pragma unroll
      for (int q = 0; q < 4; ++q) hold[jt][q] = 0.f;
  } else {                                   // restore h from previous chunk
    const int r = tid >> 5, kq = tid & 31;
    const float4* s4 = (const float4*)(wsh + ((size_t)(dir*64 + bbase + r))*256 + kq*8);
    *(f16x8*)((char*)hs + (kq>>2)*1024 + (((kq&3)*16) + r)*16) = pack8(s4[0], s4[1]);
    #pragma unroll
    for (int jt = 0; jt < 2; ++jt)
      #pragma unroll
      for (int q = 0; q < 4; ++q)
        hold[jt][q] = wsh[((size_t)(dir*64 + bbase + g*4 + q))*256 + j0 + jt*16 + lr];
  }
  __syncthreads();

  const int t0 = dir ? (1023 - sbase) : sbase;
  char* optr = (char*)out16 + ((size_t)t0*64 + bbase + g*4)*1024
             + (size_t)(dir*256 + j0 + lr)*2;
  const ptrdiff_t ostep = dir ? -(ptrdiff_t)65536 : (ptrdiff_t)65536;
  const _Float16* gp = gxc + ((size_t)(dir*CT)*4 + bsl)*12288 + (size_t)tid*8;
  const ptrdiff_t gstep = 4*12288;
  // prologue prefetch (sc=0)
  f16x8 ga0 = *(const f16x8*)(gp);
  f16x8 ga1 = *(const f16x8*)(gp + 4096);
  f16x8 ga2 = *(const f16x8*)(gp + 8192);
  gp += gstep;
  f16x8 gb0, gb1, gb2;
  f16x4 houts[2];
  bool sten = false;

  // NOTE: last prefetch overruns gxc by < 96KB, landing inside the 128KB wsh
  // slab -> in-bounds garbage, never consumed.
#define REC_STEP(RB, GC0,GC1,GC2, GN0,GN1,GN2)                                     \
  {                                                                                \
    GN0 = *(const f16x8*)(gp);                                                     \
    GN1 = *(const f16x8*)(gp + 4096);                                              \
    GN2 = *(const f16x8*)(gp + 8192);                                              \
    gp += gstep;                                                                   \
    if (sten) {                              /* store h(s-1): full step to drain */\
      _Pragma("unroll")                                                            \
      for (int jt = 0; jt < 2; ++jt)                                               \
        _Pragma("unroll")                                                          \
        for (int q = 0; q < 4; ++q)                                                \
          *(_Float16*)(optr + q*1024 + jt*32) = houts[jt][q];                      \
      optr += ostep;                                                               \
    }                                                                              \
    sten = true;                                                                   \
    f16x8 af[8];                                                                   \
    _Pragma("unroll")                                                              \
    for (int kk = 0; kk < 8; ++kk)                                                 \
      af[kk] = *(const f16x8*)(afp + (RB)*8192 + kk*1024);                         \
    f32x4 acc[6];                                                                  \
    acc[0] = acc[1] = acc[2] = acc[3] = (f32x4){0.f,0.f,0.f,0.f};                  \
    acc[4] = (f32x4){bn0,bn0,bn0,bn0};                                             \
    acc[5] = (f32x4){bn1,bn1,bn1,bn1};                                             \
    __builtin_amdgcn_s_setprio(1);                                                 \
    /* acc-major, jt0 gates' accs first: r0,z0,n0 then r1,z1,n1 */                 \
    _Pragma("unroll")                                                              \
    for (int kk = 0; kk < 8; ++kk) acc[0] = MFMA(af[kk], wf[0][kk], acc[0]);       \
    _Pragma("unroll")                                                              \
    for (int kk = 0; kk < 8; ++kk) acc[2] = MFMA(af[kk], wf[2][kk], acc[2]);       \
    _Pragma("unroll")                                                              \
    for (int kk = 0; kk < 8; ++kk) acc[4] = MFMA(af[kk], wf[4][kk], acc[4]);       \
    _Pragma("unroll")                                                              \
    for (int kk = 0; kk < 8; ++kk) acc[1] = MFMA(af[kk], wf[1][kk], acc[1]);       \
    _Pragma("unroll")                                                              \
    for (int kk = 0; kk < 8; ++kk) acc[3] = MFMA(af[kk], wf[3][kk], acc[3]);       \
    _Pragma("unroll")                                                              \
    for (int kk = 0; kk < 8; ++kk) acc[5] = MFMA(af[kk], wf[5][kk], acc[5]);       \
    __builtin_amdgcn_s_setprio(0);                                                 \
    _Pragma("unroll")                                                              \
    for (int jt = 0; jt < 2; ++jt) {                                               \
      _Pragma("unroll")                                                            \
      for (int q = 0; q < 4; ++q) {                                                \
        const float rv = __builtin_amdgcn_rcpf(                                    \
            1.f + __builtin_amdgcn_exp2f((float)GC0[jt*4+q] + acc[jt][q]));        \
        const float zv = __builtin_amdgcn_rcpf(                                    \
            1.f + __builtin_amdgcn_exp2f((float)GC1[jt*4+q] + acc[2+jt][q]));      \
        const float nv = __builtin_fmaf(-2.f, __builtin_amdgcn_rcpf(               \
            1.f + __builtin_amdgcn_exp2f(                                          \
                __builtin_fmaf(rv, acc[4+jt][q], (float)GC2[jt*4+q]))), 1.f);      \
        const float h = __builtin_fmaf(zv, hold[jt][q] - nv, nv);                  \
        hold[jt][q] = h;                                                           \
        const _Float16 hf = (_Float16)h;                                           \
        houts[jt][q] = hf;                                                         \
        *(_Float16*)(hwp + ((RB)^1)*8192 + jt*512 + q*16) = hf;                    \
      }                                                                            \
    }                                                                              \
    asm volatile("s_waitcnt lgkmcnt(0)" ::: "memory");                             \
    __builtin_amdgcn_s_barrier();                                                  \
    asm volatile("" ::: "memory");                                                 \
  }

  #pragma unroll 1
  for (int sc = 0; sc < CT; sc += 2) {
    REC_STEP(0, ga0,ga1,ga2, gb0,gb1,gb2)
    REC_STEP(1, gb0,gb1,gb2, ga0,ga1,ga2)
  }
#undef REC_STEP

  // store h(CT-1)
  #pragma unroll
  for (int jt = 0; jt < 2; ++jt)
    #pragma unroll
    for (int q = 0; q < 4; ++q)
      *(_Float16*)(optr + q*1024 + jt*32) = houts[jt][q];

  if (sbase + CT == 1024) {                  // final h -> hidden output
    #pragma unroll
    for (int jt = 0; jt < 2; ++jt)
      #pragma unroll
      for (int q = 0; q < 4; ++q)
        hidden[((size_t)(dir*64 + bbase + g*4 + q))*256 + j0 + jt*16 + lr] = hold[jt][q];
  } else {                                   // persist h for next chunk
    #pragma unroll
    for (int jt = 0; jt < 2; ++jt)
      #pragma unroll
      for (int q = 0; q < 4; ++q)
        wsh[((size_t)(dir*64 + bbase + g*4 + q))*256 + j0 + jt*16 + lr] = hold[jt][q];
  }
}

// ---------------- FC in place: relu(concat_f16 @ W_fc^T + b) -> f32 ----------------
__global__ __launch_bounds__(256) void k_fc(
    const _Float16* __restrict__ h16, const float* __restrict__ Wfc,
    const float* __restrict__ bfc, float* __restrict__ out)
{
  const int mt = blockIdx.x;
  __shared__ _Float16 As[64*512];            // 64KB
  const int tid = threadIdx.x, w = tid >> 6, l = tid & 63;
  const int lr = l & 15, g = l >> 4;
  #pragma unroll
  for (int i = 0; i < 16; ++i) {
    int c = tid + i*256, r = c >> 6, cc = c & 63;
    *(int4*)((char*)As + SWZ2(r, cc*16)) =
        *(const int4*)((const char*)h16 + ((size_t)mt*64 + r)*1024 + cc*16);
  }
  __syncthreads();                           // all h16 reads drained before any store
  #pragma unroll 1
  for (int nt = 0; nt < 4; ++nt) {
    f32x4 acc[4];
    #pragma unroll
    for (int ct = 0; ct < 4; ++ct) acc[ct] = (f32x4){0.f,0.f,0.f,0.f};
    #pragma unroll 2
    for (int kk = 0; kk < 16; ++kk) {
      f16x8 af = *(const f16x8*)((const char*)As + SWZ2(w*16 + lr, kk*64 + g*16));
      #pragma unroll
      for (int ct = 0; ct < 4; ++ct) {
        const float4* s4 = (const float4*)(Wfc + (size_t)(nt*64 + ct*16 + lr)*512 + kk*32 + g*8);
        acc[ct] = MFMA(af, pack8(s4[0], s4[1]), acc[ct]);
      }
    }
    #pragma unroll
    for (int ct = 0; ct < 4; ++ct) {
      const int col = nt*64 + ct*16 + lr;
      const float bv = bfc[col];
      #pragma unroll
      for (int q = 0; q < 4; ++q) {
        const int row = w*16 + g*4 + q;
        out[((size_t)mt*64 + row)*256 + col] = fmaxf(acc[ct][q] + bv, 0.f);
      }
    }
  }
}

extern "C" void kernel_launch(void* const* d_in, const int* in_sizes, int n_in,
                              void* d_out, int out_size, void* d_ws, size_t ws_size,
                              hipStream_t stream) {
  const float* X      = (const float*)d_in[0];
  const float* W_ih_f = (const float*)d_in[1];
  const float* W_hh_f = (const float*)d_in[2];
  const float* b_ih_f = (const float*)d_in[3];
  const float* b_hh_f = (const float*)d_in[4];
  const float* W_ih_b = (const float*)d_in[5];
  const float* W_hh_b = (const float*)d_in[6];
  const float* b_ih_b = (const float*)d_in[7];
  const float* b_hh_b = (const float*)d_in[8];
  const float* W_fc   = (const float*)d_in[9];
  const float* b_fc   = (const float*)d_in[10];

  // CT=256 keeps the gxc chunk (50MB) L3-resident (round-5 lesson: CT=1024
  // evicts its own head and exposes HBM latency per step).
  int CT = 256;
  while (CT > 8 && ((size_t)CT*196608 + 131072) > ws_size) CT >>= 1;
  _Float16* gxc = (_Float16*)d_ws;                     // [2][CT][4][3][512][8] f16
  float*    wsh = (float*)((char*)d_ws + (size_t)CT*196608);  // [2][64][256] f32

  _Float16* h16   = (_Float16*)d_out;                  // [1024][64][512] f16 (in-place)
  float*    out   = (float*)d_out;                     // [1024][64][256] f32
  float*    hidden= (float*)d_out + (size_t)1024*64*256;

  const int NC = 1024 / CT;
  for (int c = 0; c < NC; ++c) {
    k_gx<<<dim3(CT, 2), dim3(256), 0, stream>>>(X, W_ih_f, b_ih_f, b_hh_f,
                                                W_ih_b, b_ih_b, b_hh_b, gxc, CT, c*CT);
    k_rec<<<dim3(8), dim3(512), 0, stream>>>(W_hh_f, b_hh_f, W_hh_b, b_hh_b,
                                             gxc, wsh, h16, hidden, CT, c*CT);
  }
  k_fc<<<dim3(1024), dim3(256), 0, stream>>>(h16, W_fc, b_fc, out);
}

// Round 7
// 3231.119 us; speedup vs baseline: 1.3781x; 1.3409x over previous
//
#include <hip/hip_runtime.h>
#include <hip/hip_fp16.h>

// Bidirectional GRU (B=64,S=1024,E=H=256) + FC/ReLU head — chunked pipeline.
// k_gx: gx = x@W_ih^T (+biases), f16 MFMA; output PRE-SCALED by -log2e (r,z) /
//       +2log2e (n) so k_rec gates use exp2 directly; consumer layout
//       [dir][t][bsl][gate][tid512][8] -> 16B-aligned f16x8 loads.
// k_rec: persistent 8 WGs (2 dir x 4 bslice) x 512 thr. W_hh f16 frags
//        reg-resident, pre-scaled. h in LDS in MFMA-A-frag order (linear
//        conflict-free ds_read_b128). Ping-pong h tiles; raw s_barrier +
//        lgkm-only waitcnt; gx prefetch 1 step ahead; out stores deferred.
//        MFMA in TWO kk-major groups {0,2,4} then {1,3,5} (dep distance 3,
//        issue-bound with 2-wave interleave) with jt=0 gate VALU between
//        groups so it schedules under group 2's MFMAs. No setprio.
// k_fc: relu(concat @ W_fc^T + b) in place over f16 h written into d_out.

typedef _Float16 f16x8 __attribute__((ext_vector_type(8)));
typedef _Float16 f16x4 __attribute__((ext_vector_type(4)));
typedef float    f32x4 __attribute__((ext_vector_type(4)));

#define MFMA(a,b,c) __builtin_amdgcn_mfma_f32_16x16x32_f16((a),(b),(c),0,0,0)
#define SWZ(r,c)  ((((r)*512)  + (c)) ^ (((r)&7)<<4))
#define SWZ2(r,c) ((((r)*1024) + (c)) ^ (((r)&7)<<4))

#define NLOG2E (-1.442695041f)
#define P2LOG2E (2.885390082f)

__device__ inline f16x8 pack8(float4 a, float4 b){
  f16x8 h;
  h[0]=(_Float16)a.x; h[1]=(_Float16)a.y; h[2]=(_Float16)a.z; h[3]=(_Float16)a.w;
  h[4]=(_Float16)b.x; h[5]=(_Float16)b.y; h[6]=(_Float16)b.z; h[7]=(_Float16)b.w;
  return h;
}
__device__ inline f16x8 pack8s(float4 a, float4 b, float s){
  f16x8 h;
  h[0]=(_Float16)(a.x*s); h[1]=(_Float16)(a.y*s); h[2]=(_Float16)(a.z*s); h[3]=(_Float16)(a.w*s);
  h[4]=(_Float16)(b.x*s); h[5]=(_Float16)(b.y*s); h[6]=(_Float16)(b.z*s); h[7]=(_Float16)(b.w*s);
  return h;
}

// ---------------- gx: gx = scale * (x @ W_ih^T + b_ih (+ b_hh for r,z)) ----------------
__global__ __launch_bounds__(256) void k_gx(
    const float* __restrict__ X,
    const float* __restrict__ Wf, const float* __restrict__ bihf, const float* __restrict__ bhhf,
    const float* __restrict__ Wb, const float* __restrict__ bihb, const float* __restrict__ bhhb,
    _Float16* __restrict__ gxc, int CT, int sbase)
{
  const int tc = blockIdx.x, dir = blockIdx.y;
  const int p = sbase + tc;
  const int t = dir ? (1023 - p) : p;
  const float* __restrict__ Wp = dir ? Wb : Wf;
  const float* __restrict__ bi = dir ? bihb : bihf;
  const float* __restrict__ bh = dir ? bhhb : bhhf;
  __shared__ _Float16 As[64*256];            // 32KB
  __shared__ _Float16 Bs[64*256];            // 32KB
  const int tid = threadIdx.x;
  #pragma unroll
  for (int i = 0; i < 8; ++i) {              // stage A: rows = batch b, fixed t
    int c = tid + i*256, r = c >> 5, cc = c & 31;
    const float4* s4 = (const float4*)(X + ((size_t)r*1024 + t)*256 + cc*8);
    *(f16x8*)((char*)As + SWZ(r, cc*16)) = pack8(s4[0], s4[1]);
  }
  const int w = tid >> 6, l = tid & 63, lr = l & 15, g = l >> 4;
  const size_t obase = (((size_t)dir*CT + tc)*4 + w) * (size_t)12288;  // f16 units
  #pragma unroll 1
  for (int nt = 0; nt < 12; ++nt) {
    __syncthreads();
    #pragma unroll
    for (int i = 0; i < 8; ++i) {            // stage B: W rows nt*64..+64
      int c = tid + i*256, r = c >> 5, cc = c & 31;
      const float4* s4 = (const float4*)(Wp + (size_t)(nt*64 + r)*256 + cc*8);
      *(f16x8*)((char*)Bs + SWZ(r, cc*16)) = pack8(s4[0], s4[1]);
    }
    __syncthreads();
    f32x4 acc[4];
    #pragma unroll
    for (int ct = 0; ct < 4; ++ct) acc[ct] = (f32x4){0.f,0.f,0.f,0.f};
    #pragma unroll
    for (int kk = 0; kk < 8; ++kk) {
      f16x8 af = *(const f16x8*)((const char*)As + SWZ(w*16 + lr, kk*64 + g*16));
      #pragma unroll
      for (int ct = 0; ct < 4; ++ct) {
        f16x8 bfr = *(const f16x8*)((const char*)Bs + SWZ(ct*16 + lr, kk*64 + g*16));
        acc[ct] = MFMA(af, bfr, acc[ct]);
      }
    }
    #pragma unroll
    for (int ct = 0; ct < 4; ++ct) {         // consumer layout [gate][tid512][8]
      const int col = nt*64 + ct*16 + lr;
      const int gate = col >> 8;
      const float sc = (gate == 2) ? P2LOG2E : NLOG2E;
      const float bv = bi[col] + (gate < 2 ? bh[col] : 0.f);
      const int j = col & 255;
      const int tid2 = (j>>5)*64 + g*16 + (j&15);
      const int off = ((j>>4)&1)*4;          // jt*4
      f16x4 v;
      #pragma unroll
      for (int q = 0; q < 4; ++q) v[q] = (_Float16)((acc[ct][q] + bv)*sc);
      *(f16x4*)(gxc + obase + gate*4096 + tid2*8 + off) = v;
    }
  }
}

// ---------------- GRU recurrence, one chunk of CT steps ----------------
// h tile in A-frag order: h[r][k] at byte (k>>5)*1024 + ((k>>3)&3)*256 + r*16 + (k&7)*2;
// af read for kk = ds_read_b128 at l*16 + kk*1024 (linear, conflict-free).
// Thread (w,l) produces h[g*4+q][w*32+jt*16+lr].
// Gates (pre-scaled): r = rcp(1+exp2(xr'+hr')), z likewise,
//                     n = 1 - 2*rcp(1+exp2(xn' + r*hn')), h = n + z*(h_old-n).
__global__ __launch_bounds__(512, 2) void k_rec(
    const float* __restrict__ Whh_f, const float* __restrict__ bhh_f,
    const float* __restrict__ Whh_b, const float* __restrict__ bhh_b,
    const _Float16* __restrict__ gxc, float* __restrict__ wsh,
    _Float16* __restrict__ out16, float* __restrict__ hidden,
    int CT, int sbase)
{
  const int dir = blockIdx.x & 1;
  const int bsl = blockIdx.x >> 1;
  const int bbase = bsl * 16;
  const float* __restrict__ Whh = dir ? Whh_b : Whh_f;
  const float* __restrict__ bhh = dir ? bhh_b : bhh_f;
  const int tid = threadIdx.x, w = tid >> 6, l = tid & 63;
  const int lr = l & 15, g = l >> 4;
  const int j0 = w * 32;
  f16x8 wf[6][8];                            // B-frag: W[col][k=kk*32+g*8+i], pre-scaled
  #pragma unroll
  for (int ct = 0; ct < 6; ++ct) {
    const int colg = (ct>>1)*256 + j0 + (ct&1)*16 + lr;
    const float scl = (ct < 4) ? NLOG2E : P2LOG2E;
    #pragma unroll
    for (int kk = 0; kk < 8; ++kk) {
      const float4* s4 = (const float4*)(Whh + (size_t)colg*256 + kk*32 + g*8);
      wf[ct][kk] = pack8s(s4[0], s4[1], scl);
    }
  }
  const float bn0 = P2LOG2E * bhh[512 + j0 + lr];        // n-gate bhh, pre-scaled
  const float bn1 = P2LOG2E * bhh[512 + j0 + 16 + lr];
  __shared__ _Float16 hs[2][4096];           // ping-pong A-frag-ordered h tiles (16KB)
  char* const afp = (char*)hs + l*16;
  char* const hwp = (char*)hs + w*1024 + (lr>>3)*256 + g*64 + (lr&7)*2;
  float hold[2][4];
  if (sbase == 0) {
    *(int4*)((char*)hs + tid*16) = make_int4(0,0,0,0);   // hs[0] := 0 (8KB exact)
    #pragma unroll
    for (int jt = 0; jt < 2; ++jt)
      #pragma unroll
      for (int q = 0; q < 4; ++q) hold[jt][q] = 0.f;
  } else {                                   // restore h from previous chunk
    const int r = tid >> 5, kq = tid & 31;
    const float4* s4 = (const float4*)(wsh + ((size_t)(dir*64 + bbase + r))*256 + kq*8);
    *(f16x8*)((char*)hs + (kq>>2)*1024 + (((kq&3)*16) + r)*16) = pack8(s4[0], s4[1]);
    #pragma unroll
    for (int jt = 0; jt < 2; ++jt)
      #pragma unroll
      for (int q = 0; q < 4; ++q)
        hold[jt][q] = wsh[((size_t)(dir*64 + bbase + g*4 + q))*256 + j0 + jt*16 + lr];
  }
  __syncthreads();

  const int t0 = dir ? (1023 - sbase) : sbase;
  char* optr = (char*)out16 + ((size_t)t0*64 + bbase + g*4)*1024
             + (size_t)(dir*256 + j0 + lr)*2;
  const ptrdiff_t ostep = dir ? -(ptrdiff_t)65536 : (ptrdiff_t)65536;
  const _Float16* gp = gxc + ((size_t)(dir*CT)*4 + bsl)*12288 + (size_t)tid*8;
  const ptrdiff_t gstep = 4*12288;
  // prologue prefetch (sc=0)
  f16x8 ga0 = *(const f16x8*)(gp);
  f16x8 ga1 = *(const f16x8*)(gp + 4096);
  f16x8 ga2 = *(const f16x8*)(gp + 8192);
  gp += gstep;
  f16x8 gb0, gb1, gb2;
  f16x4 houts[2];
  bool sten = false;

  // NOTE: last prefetch overruns gxc by < 96KB, landing inside the 128KB wsh
  // slab -> in-bounds garbage, never consumed.
#define REC_STEP(RB, GC0,GC1,GC2, GN0,GN1,GN2)                                     \
  {                                                                                \
    GN0 = *(const f16x8*)(gp);                                                     \
    GN1 = *(const f16x8*)(gp + 4096);                                              \
    GN2 = *(const f16x8*)(gp + 8192);                                              \
    gp += gstep;                                                                   \
    if (sten) {                              /* store h(s-1): full step to drain */\
      _Pragma("unroll")                                                            \
      for (int jt = 0; jt < 2; ++jt)                                               \
        _Pragma("unroll")                                                          \
        for (int q = 0; q < 4; ++q)                                                \
          *(_Float16*)(optr + q*1024 + jt*32) = houts[jt][q];                      \
      optr += ostep;                                                               \
    }                                                                              \
    sten = true;                                                                   \
    f16x8 af[8];                                                                   \
    _Pragma("unroll")                                                              \
    for (int kk = 0; kk < 8; ++kk)                                                 \
      af[kk] = *(const f16x8*)(afp + (RB)*8192 + kk*1024);                         \
    f32x4 acc0 = (f32x4){0.f,0.f,0.f,0.f};                                         \
    f32x4 acc2 = (f32x4){0.f,0.f,0.f,0.f};                                         \
    f32x4 acc4 = (f32x4){bn0,bn0,bn0,bn0};                                         \
    /* group 1: jt=0 accs, kk-major (dep distance 3) */                            \
    _Pragma("unroll")                                                              \
    for (int kk = 0; kk < 8; ++kk) {                                               \
      acc0 = MFMA(af[kk], wf[0][kk], acc0);                                        \
      acc2 = MFMA(af[kk], wf[2][kk], acc2);                                        \
      acc4 = MFMA(af[kk], wf[4][kk], acc4);                                        \
    }                                                                              \
    /* jt=0 gates: schedulable under group 2's MFMAs */                            \
    f32x4 acc1 = (f32x4){0.f,0.f,0.f,0.f};                                         \
    f32x4 acc3 = (f32x4){0.f,0.f,0.f,0.f};                                         \
    f32x4 acc5 = (f32x4){bn1,bn1,bn1,bn1};                                         \
    _Pragma("unroll")                                                              \
    for (int q = 0; q < 4; ++q) {                                                  \
      const float rv = __builtin_amdgcn_rcpf(                                      \
          1.f + __builtin_amdgcn_exp2f((float)GC0[q] + acc0[q]));                  \
      const float zv = __builtin_amdgcn_rcpf(                                      \
          1.f + __builtin_amdgcn_exp2f((float)GC1[q] + acc2[q]));                  \
      const float nv = __builtin_fmaf(-2.f, __builtin_amdgcn_rcpf(                 \
          1.f + __builtin_amdgcn_exp2f(                                            \
              __builtin_fmaf(rv, acc4[q], (float)GC2[q]))), 1.f);                  \
      const float h = __builtin_fmaf(zv, hold[0][q] - nv, nv);                     \
      hold[0][q] = h;                                                              \
      const _Float16 hf = (_Float16)h;                                             \
      houts[0][q] = hf;                                                            \
      *(_Float16*)(hwp + ((RB)^1)*8192 + q*16) = hf;                               \
    }                                                                              \
    /* group 2: jt=1 accs, kk-major */                                             \
    _Pragma("unroll")                                                              \
    for (int kk = 0; kk < 8; ++kk) {                                               \
      acc1 = MFMA(af[kk], wf[1][kk], acc1);                                        \
      acc3 = MFMA(af[kk], wf[3][kk], acc3);                                        \
      acc5 = MFMA(af[kk], wf[5][kk], acc5);                                        \
    }                                                                              \
    _Pragma("unroll")                                                              \
    for (int q = 0; q < 4; ++q) {                                                  \
      const float rv = __builtin_amdgcn_rcpf(                                      \
          1.f + __builtin_amdgcn_exp2f((float)GC0[4+q] + acc1[q]));                \
      const float zv = __builtin_amdgcn_rcpf(                                      \
          1.f + __builtin_amdgcn_exp2f((float)GC1[4+q] + acc3[q]));                \
      const float nv = __builtin_fmaf(-2.f, __builtin_amdgcn_rcpf(                 \
          1.f + __builtin_amdgcn_exp2f(                                            \
              __builtin_fmaf(rv, acc5[q], (float)GC2[4+q]))), 1.f);                \
      const float h = __builtin_fmaf(zv, hold[1][q] - nv, nv);                     \
      hold[1][q] = h;                                                              \
      const _Float16 hf = (_Float16)h;                                             \
      houts[1][q] = hf;                                                            \
      *(_Float16*)(hwp + ((RB)^1)*8192 + 512 + q*16) = hf;                         \
    }                                                                              \
    asm volatile("s_waitcnt lgkmcnt(0)" ::: "memory");                             \
    __builtin_amdgcn_s_barrier();                                                  \
    asm volatile("" ::: "memory");                                                 \
  }

  #pragma unroll 1
  for (int sc = 0; sc < CT; sc += 2) {
    REC_STEP(0, ga0,ga1,ga2, gb0,gb1,gb2)
    REC_STEP(1, gb0,gb1,gb2, ga0,ga1,ga2)
  }
#undef REC_STEP

  // store h(CT-1)
  #pragma unroll
  for (int jt = 0; jt < 2; ++jt)
    #pragma unroll
    for (int q = 0; q < 4; ++q)
      *(_Float16*)(optr + q*1024 + jt*32) = houts[jt][q];

  if (sbase + CT == 1024) {                  // final h -> hidden output
    #pragma unroll
    for (int jt = 0; jt < 2; ++jt)
      #pragma unroll
      for (int q = 0; q < 4; ++q)
        hidden[((size_t)(dir*64 + bbase + g*4 + q))*256 + j0 + jt*16 + lr] = hold[jt][q];
  } else {                                   // persist h for next chunk
    #pragma unroll
    for (int jt = 0; jt < 2; ++jt)
      #pragma unroll
      for (int q = 0; q < 4; ++q)
        wsh[((size_t)(dir*64 + bbase + g*4 + q))*256 + j0 + jt*16 + lr] = hold[jt][q];
  }
}

// ---------------- FC in place: relu(concat_f16 @ W_fc^T + b) -> f32 ----------------
__global__ __launch_bounds__(256) void k_fc(
    const _Float16* __restrict__ h16, const float* __restrict__ Wfc,
    const float* __restrict__ bfc, float* __restrict__ out)
{
  const int mt = blockIdx.x;
  __shared__ _Float16 As[64*512];            // 64KB
  const int tid = threadIdx.x, w = tid >> 6, l = tid & 63;
  const int lr = l & 15, g = l >> 4;
  #pragma unroll
  for (int i = 0; i < 16; ++i) {
    int c = tid + i*256, r = c >> 6, cc = c & 63;
    *(int4*)((char*)As + SWZ2(r, cc*16)) =
        *(const int4*)((const char*)h16 + ((size_t)mt*64 + r)*1024 + cc*16);
  }
  __syncthreads();                           // all h16 reads drained before any store
  #pragma unroll 1
  for (int nt = 0; nt < 4; ++nt) {
    f32x4 acc[4];
    #pragma unroll
    for (int ct = 0; ct < 4; ++ct) acc[ct] = (f32x4){0.f,0.f,0.f,0.f};
    #pragma unroll 2
    for (int kk = 0; kk < 16; ++kk) {
      f16x8 af = *(const f16x8*)((const char*)As + SWZ2(w*16 + lr, kk*64 + g*16));
      #pragma unroll
      for (int ct = 0; ct < 4; ++ct) {
        const float4* s4 = (const float4*)(Wfc + (size_t)(nt*64 + ct*16 + lr)*512 + kk*32 + g*8);
        acc[ct] = MFMA(af, pack8(s4[0], s4[1]), acc[ct]);
      }
    }
    #pragma unroll
    for (int ct = 0; ct < 4; ++ct) {
      const int col = nt*64 + ct*16 + lr;
      const float bv = bfc[col];
      #pragma unroll
      for (int q = 0; q < 4; ++q) {
        const int row = w*16 + g*4 + q;
        out[((size_t)mt*64 + row)*256 + col] = fmaxf(acc[ct][q] + bv, 0.f);
      }
    }
  }
}

extern "C" void kernel_launch(void* const* d_in, const int* in_sizes, int n_in,
                              void* d_out, int out_size, void* d_ws, size_t ws_size,
                              hipStream_t stream) {
  const float* X      = (const float*)d_in[0];
  const float* W_ih_f = (const float*)d_in[1];
  const float* W_hh_f = (const float*)d_in[2];
  const float* b_ih_f = (const float*)d_in[3];
  const float* b_hh_f = (const float*)d_in[4];
  const float* W_ih_b = (const float*)d_in[5];
  const float* W_hh_b = (const float*)d_in[6];
  const float* b_ih_b = (const float*)d_in[7];
  const float* b_hh_b = (const float*)d_in[8];
  const float* W_fc   = (const float*)d_in[9];
  const float* b_fc   = (const float*)d_in[10];

  // CT=256 keeps the gxc chunk (50MB) L3-resident (round-5 lesson: CT=1024
  // evicts its own head and exposes HBM latency per step).
  int CT = 256;
  while (CT > 8 && ((size_t)CT*196608 + 131072) > ws_size) CT >>= 1;
  _Float16* gxc = (_Float16*)d_ws;                     // [2][CT][4][3][512][8] f16
  float*    wsh = (float*)((char*)d_ws + (size_t)CT*196608);  // [2][64][256] f32

  _Float16* h16   = (_Float16*)d_out;                  // [1024][64][512] f16 (in-place)
  float*    out   = (float*)d_out;                     // [1024][64][256] f32
  float*    hidden= (float*)d_out + (size_t)1024*64*256;

  const int NC = 1024 / CT;
  for (int c = 0; c < NC; ++c) {
    k_gx<<<dim3(CT, 2), dim3(256), 0, stream>>>(X, W_ih_f, b_ih_f, b_hh_f,
                                                W_ih_b, b_ih_b, b_hh_b, gxc, CT, c*CT);
    k_rec<<<dim3(8), dim3(512), 0, stream>>>(W_hh_f, b_hh_f, W_hh_b, b_hh_b,
                                             gxc, wsh, h16, hidden, CT, c*CT);
  }
  k_fc<<<dim3(1024), dim3(256), 0, stream>>>(h16, W_fc, b_fc, out);
}

// Round 8
// 2292.289 us; speedup vs baseline: 1.9425x; 1.4096x over previous
//
#include <hip/hip_runtime.h>
#include <hip/hip_fp16.h>

// Bidirectional GRU (B=64,S=1024,E=H=256) + FC/ReLU head — chunked pipeline.
// k_gx: gx = x@W_ih^T (+biases), f16 MFMA; PRE-SCALED by -log2e (r,z) / +2log2e (n);
//       consumer layout [dir][t][bsl][tid512][3 gates][8] -> one base, imm offsets.
// k_rec: persistent 8 WGs (2dir x 4bslice) x 512 thr, launch_bounds(512,2).
//        REGISTER-FRUGAL: peak live ~245 < 256 unified so W_hh frags stay in
//        arch VGPRs (no AGPR copy traffic): one acc set reused across the two
//        jt groups, af read inline per kk (re-read per group), gx single-buffer
//        loaded post-barrier (consumed after group1), immediate out stores.
//        h in LDS in MFMA-A-frag order (linear conflict-free ds_read_b128),
//        ping-pong tiles, raw s_barrier + lgkm-only waitcnt.
// k_fc: relu(concat @ W_fc^T + b) in place over f16 h written into d_out.

typedef _Float16 f16x8 __attribute__((ext_vector_type(8)));
typedef _Float16 f16x4 __attribute__((ext_vector_type(4)));
typedef float    f32x4 __attribute__((ext_vector_type(4)));

#define MFMA(a,b,c) __builtin_amdgcn_mfma_f32_16x16x32_f16((a),(b),(c),0,0,0)
#define SWZ(r,c)  ((((r)*512)  + (c)) ^ (((r)&7)<<4))
#define SWZ2(r,c) ((((r)*1024) + (c)) ^ (((r)&7)<<4))

#define NLOG2E (-1.442695041f)
#define P2LOG2E (2.885390082f)

__device__ inline f16x8 pack8(float4 a, float4 b){
  f16x8 h;
  h[0]=(_Float16)a.x; h[1]=(_Float16)a.y; h[2]=(_Float16)a.z; h[3]=(_Float16)a.w;
  h[4]=(_Float16)b.x; h[5]=(_Float16)b.y; h[6]=(_Float16)b.z; h[7]=(_Float16)b.w;
  return h;
}
__device__ inline f16x8 pack8s(float4 a, float4 b, float s){
  f16x8 h;
  h[0]=(_Float16)(a.x*s); h[1]=(_Float16)(a.y*s); h[2]=(_Float16)(a.z*s); h[3]=(_Float16)(a.w*s);
  h[4]=(_Float16)(b.x*s); h[5]=(_Float16)(b.y*s); h[6]=(_Float16)(b.z*s); h[7]=(_Float16)(b.w*s);
  return h;
}

// ---------------- gx: gx = scale * (x @ W_ih^T + b_ih (+ b_hh for r,z)) ----------------
__global__ __launch_bounds__(256) void k_gx(
    const float* __restrict__ X,
    const float* __restrict__ Wf, const float* __restrict__ bihf, const float* __restrict__ bhhf,
    const float* __restrict__ Wb, const float* __restrict__ bihb, const float* __restrict__ bhhb,
    _Float16* __restrict__ gxc, int CT, int sbase)
{
  const int tc = blockIdx.x, dir = blockIdx.y;
  const int p = sbase + tc;
  const int t = dir ? (1023 - p) : p;
  const float* __restrict__ Wp = dir ? Wb : Wf;
  const float* __restrict__ bi = dir ? bihb : bihf;
  const float* __restrict__ bh = dir ? bhhb : bhhf;
  __shared__ _Float16 As[64*256];            // 32KB
  __shared__ _Float16 Bs[64*256];            // 32KB
  const int tid = threadIdx.x;
  #pragma unroll
  for (int i = 0; i < 8; ++i) {              // stage A: rows = batch b, fixed t
    int c = tid + i*256, r = c >> 5, cc = c & 31;
    const float4* s4 = (const float4*)(X + ((size_t)r*1024 + t)*256 + cc*8);
    *(f16x8*)((char*)As + SWZ(r, cc*16)) = pack8(s4[0], s4[1]);
  }
  const int w = tid >> 6, l = tid & 63, lr = l & 15, g = l >> 4;
  const size_t obase = (((size_t)dir*CT + tc)*4 + w) * (size_t)12288;  // f16 units
  #pragma unroll 1
  for (int nt = 0; nt < 12; ++nt) {
    __syncthreads();
    #pragma unroll
    for (int i = 0; i < 8; ++i) {            // stage B: W rows nt*64..+64
      int c = tid + i*256, r = c >> 5, cc = c & 31;
      const float4* s4 = (const float4*)(Wp + (size_t)(nt*64 + r)*256 + cc*8);
      *(f16x8*)((char*)Bs + SWZ(r, cc*16)) = pack8(s4[0], s4[1]);
    }
    __syncthreads();
    f32x4 acc[4];
    #pragma unroll
    for (int ct = 0; ct < 4; ++ct) acc[ct] = (f32x4){0.f,0.f,0.f,0.f};
    #pragma unroll
    for (int kk = 0; kk < 8; ++kk) {
      f16x8 af = *(const f16x8*)((const char*)As + SWZ(w*16 + lr, kk*64 + g*16));
      #pragma unroll
      for (int ct = 0; ct < 4; ++ct) {
        f16x8 bfr = *(const f16x8*)((const char*)Bs + SWZ(ct*16 + lr, kk*64 + g*16));
        acc[ct] = MFMA(af, bfr, acc[ct]);
      }
    }
    #pragma unroll
    for (int ct = 0; ct < 4; ++ct) {         // consumer layout [tid512][3][8]
      const int col = nt*64 + ct*16 + lr;
      const int gate = col >> 8;
      const float sc = (gate == 2) ? P2LOG2E : NLOG2E;
      const float bv = bi[col] + (gate < 2 ? bh[col] : 0.f);
      const int j = col & 255;
      const int tid2 = (j>>5)*64 + g*16 + (j&15);
      const int off = ((j>>4)&1)*4;          // jt*4
      f16x4 v;
      #pragma unroll
      for (int q = 0; q < 4; ++q) v[q] = (_Float16)((acc[ct][q] + bv)*sc);
      *(f16x4*)(gxc + obase + (size_t)tid2*24 + gate*8 + off) = v;
    }
  }
}

// ---------------- GRU recurrence, one chunk of CT steps ----------------
// h tile in A-frag order: h[r][k] at byte (k>>5)*1024 + ((k>>3)&3)*256 + r*16 + (k&7)*2;
// af read for kk = ds_read_b128 at l*16 + kk*1024 (linear, conflict-free).
// Thread (w,l) produces h[g*4+q][w*32+jt*16+lr].
// Gates (pre-scaled): r = rcp(1+exp2(xr'+hr')), z likewise,
//                     n = 1 - 2*rcp(1+exp2(xn' + r*hn')), h = n + z*(h_old-n).
__global__ __launch_bounds__(512, 2) void k_rec(
    const float* __restrict__ Whh_f, const float* __restrict__ bhh_f,
    const float* __restrict__ Whh_b, const float* __restrict__ bhh_b,
    const _Float16* __restrict__ gxc, float* __restrict__ wsh,
    _Float16* __restrict__ out16, float* __restrict__ hidden,
    int CT, int sbase)
{
  const int dir = blockIdx.x & 1;
  const int bsl = blockIdx.x >> 1;
  const int bbase = bsl * 16;
  const float* __restrict__ Whh = dir ? Whh_b : Whh_f;
  const float* __restrict__ bhh = dir ? bhh_b : bhh_f;
  const int tid = threadIdx.x, w = tid >> 6, l = tid & 63;
  const int lr = l & 15, g = l >> 4;
  const int j0 = w * 32;
  f16x8 wf[6][8];                            // B-frag: W[col][k=kk*32+g*8+i], pre-scaled
  #pragma unroll
  for (int ct = 0; ct < 6; ++ct) {
    const int colg = (ct>>1)*256 + j0 + (ct&1)*16 + lr;
    const float scl = (ct < 4) ? NLOG2E : P2LOG2E;
    #pragma unroll
    for (int kk = 0; kk < 8; ++kk) {
      const float4* s4 = (const float4*)(Whh + (size_t)colg*256 + kk*32 + g*8);
      wf[ct][kk] = pack8s(s4[0], s4[1], scl);
    }
  }
  const float bn0 = P2LOG2E * bhh[512 + j0 + lr];        // n-gate bhh, pre-scaled
  const float bn1 = P2LOG2E * bhh[512 + j0 + 16 + lr];
  __shared__ _Float16 hs[2][4096];           // ping-pong A-frag-ordered h tiles (16KB)
  char* const afp = (char*)hs + l*16;
  char* const hwp = (char*)hs + w*1024 + (lr>>3)*256 + g*64 + (lr&7)*2;
  float hold[2][4];
  if (sbase == 0) {
    *(int4*)((char*)hs + tid*16) = make_int4(0,0,0,0);   // hs[0] := 0 (8KB exact)
    #pragma unroll
    for (int jt = 0; jt < 2; ++jt)
      #pragma unroll
      for (int q = 0; q < 4; ++q) hold[jt][q] = 0.f;
  } else {                                   // restore h from previous chunk
    const int r = tid >> 5, kq = tid & 31;
    const float4* s4 = (const float4*)(wsh + ((size_t)(dir*64 + bbase + r))*256 + kq*8);
    *(f16x8*)((char*)hs + (kq>>2)*1024 + (((kq&3)*16) + r)*16) = pack8(s4[0], s4[1]);
    #pragma unroll
    for (int jt = 0; jt < 2; ++jt)
      #pragma unroll
      for (int q = 0; q < 4; ++q)
        hold[jt][q] = wsh[((size_t)(dir*64 + bbase + g*4 + q))*256 + j0 + jt*16 + lr];
  }
  __syncthreads();

  const int t0 = dir ? (1023 - sbase) : sbase;
  char* optr = (char*)out16 + ((size_t)t0*64 + bbase + g*4)*1024
             + (size_t)(dir*256 + j0 + lr)*2;
  const ptrdiff_t ostep = dir ? -(ptrdiff_t)65536 : (ptrdiff_t)65536;
  const _Float16* gp = gxc + ((size_t)(dir*CT)*4 + bsl)*12288 + (size_t)tid*24;
  const ptrdiff_t gstep = 4*12288;

// One step: gx loads (consumed after group1's ~1000cyc MFMA phase) ->
// group1 MFMA (jt0 tiles, af inline) -> gates jt0 (reuses then frees accs) ->
// group2 MFMA (jt1 tiles, same acc regs) -> gates jt1 -> lgkm-only barrier.
#define REC_STEP(RB)                                                               \
  {                                                                                \
    const f16x8 gv0 = *(const f16x8*)(gp);                                         \
    const f16x8 gv1 = *(const f16x8*)(gp + 8);                                     \
    const f16x8 gv2 = *(const f16x8*)(gp + 16);                                    \
    gp += gstep;                                                                   \
    {                                                                              \
      f32x4 ar = (f32x4){0.f,0.f,0.f,0.f};                                         \
      f32x4 az = (f32x4){0.f,0.f,0.f,0.f};                                         \
      f32x4 an = (f32x4){bn0,bn0,bn0,bn0};                                         \
      _Pragma("unroll")                                                            \
      for (int kk = 0; kk < 8; ++kk) {                                             \
        const f16x8 af = *(const f16x8*)(afp + (RB)*8192 + kk*1024);               \
        ar = MFMA(af, wf[0][kk], ar);                                              \
        az = MFMA(af, wf[2][kk], az);                                              \
        an = MFMA(af, wf[4][kk], an);                                              \
      }                                                                            \
      _Pragma("unroll")                                                            \
      for (int q = 0; q < 4; ++q) {                                                \
        const float rv = __builtin_amdgcn_rcpf(                                    \
            1.f + __builtin_amdgcn_exp2f((float)gv0[q] + ar[q]));                  \
        const float zv = __builtin_amdgcn_rcpf(                                    \
            1.f + __builtin_amdgcn_exp2f((float)gv1[q] + az[q]));                  \
        const float nv = __builtin_fmaf(-2.f, __builtin_amdgcn_rcpf(               \
            1.f + __builtin_amdgcn_exp2f(                                          \
                __builtin_fmaf(rv, an[q], (float)gv2[q]))), 1.f);                  \
        const float h = __builtin_fmaf(zv, hold[0][q] - nv, nv);                   \
        hold[0][q] = h;                                                            \
        const _Float16 hf = (_Float16)h;                                           \
        *(_Float16*)(hwp + ((RB)^1)*8192 + q*16) = hf;                             \
        *(_Float16*)(optr + q*1024) = hf;                                          \
      }                                                                            \
    }                                                                              \
    {                                                                              \
      f32x4 ar = (f32x4){0.f,0.f,0.f,0.f};                                         \
      f32x4 az = (f32x4){0.f,0.f,0.f,0.f};                                         \
      f32x4 an = (f32x4){bn1,bn1,bn1,bn1};                                         \
      _Pragma("unroll")                                                            \
      for (int kk = 0; kk < 8; ++kk) {                                             \
        const f16x8 af = *(const f16x8*)(afp + (RB)*8192 + kk*1024);               \
        ar = MFMA(af, wf[1][kk], ar);                                              \
        az = MFMA(af, wf[3][kk], az);                                              \
        an = MFMA(af, wf[5][kk], an);                                              \
      }                                                                            \
      _Pragma("unroll")                                                            \
      for (int q = 0; q < 4; ++q) {                                                \
        const float rv = __builtin_amdgcn_rcpf(                                    \
            1.f + __builtin_amdgcn_exp2f((float)gv0[4+q] + ar[q]));                \
        const float zv = __builtin_amdgcn_rcpf(                                    \
            1.f + __builtin_amdgcn_exp2f((float)gv1[4+q] + az[q]));                \
        const float nv = __builtin_fmaf(-2.f, __builtin_amdgcn_rcpf(               \
            1.f + __builtin_amdgcn_exp2f(                                          \
                __builtin_fmaf(rv, an[q], (float)gv2[4+q]))), 1.f);                \
        const float h = __builtin_fmaf(zv, hold[1][q] - nv, nv);                   \
        hold[1][q] = h;                                                            \
        const _Float16 hf = (_Float16)h;                                           \
        *(_Float16*)(hwp + ((RB)^1)*8192 + 512 + q*16) = hf;                       \
        *(_Float16*)(optr + q*1024 + 32) = hf;                                     \
      }                                                                            \
    }                                                                              \
    optr += ostep;                                                                 \
    asm volatile("s_waitcnt lgkmcnt(0)" ::: "memory");                             \
    __builtin_amdgcn_s_barrier();                                                  \
    asm volatile("" ::: "memory");                                                 \
  }

  #pragma unroll 1
  for (int sc = 0; sc < CT; sc += 2) {
    REC_STEP(0)
    REC_STEP(1)
  }
#undef REC_STEP

  if (sbase + CT == 1024) {                  // final h -> hidden output
    #pragma unroll
    for (int jt = 0; jt < 2; ++jt)
      #pragma unroll
      for (int q = 0; q < 4; ++q)
        hidden[((size_t)(dir*64 + bbase + g*4 + q))*256 + j0 + jt*16 + lr] = hold[jt][q];
  } else {                                   // persist h for next chunk
    #pragma unroll
    for (int jt = 0; jt < 2; ++jt)
      #pragma unroll
      for (int q = 0; q < 4; ++q)
        wsh[((size_t)(dir*64 + bbase + g*4 + q))*256 + j0 + jt*16 + lr] = hold[jt][q];
  }
}

// ---------------- FC in place: relu(concat_f16 @ W_fc^T + b) -> f32 ----------------
__global__ __launch_bounds__(256) void k_fc(
    const _Float16* __restrict__ h16, const float* __restrict__ Wfc,
    const float* __restrict__ bfc, float* __restrict__ out)
{
  const int mt = blockIdx.x;
  __shared__ _Float16 As[64*512];            // 64KB
  const int tid = threadIdx.x, w = tid >> 6, l = tid & 63;
  const int lr = l & 15, g = l >> 4;
  #pragma unroll
  for (int i = 0; i < 16; ++i) {
    int c = tid + i*256, r = c >> 6, cc = c & 63;
    *(int4*)((char*)As + SWZ2(r, cc*16)) =
        *(const int4*)((const char*)h16 + ((size_t)mt*64 + r)*1024 + cc*16);
  }
  __syncthreads();                           // all h16 reads drained before any store
  #pragma unroll 1
  for (int nt = 0; nt < 4; ++nt) {
    f32x4 acc[4];
    #pragma unroll
    for (int ct = 0; ct < 4; ++ct) acc[ct] = (f32x4){0.f,0.f,0.f,0.f};
    #pragma unroll 2
    for (int kk = 0; kk < 16; ++kk) {
      f16x8 af = *(const f16x8*)((const char*)As + SWZ2(w*16 + lr, kk*64 + g*16));
      #pragma unroll
      for (int ct = 0; ct < 4; ++ct) {
        const float4* s4 = (const float4*)(Wfc + (size_t)(nt*64 + ct*16 + lr)*512 + kk*32 + g*8);
        acc[ct] = MFMA(af, pack8(s4[0], s4[1]), acc[ct]);
      }
    }
    #pragma unroll
    for (int ct = 0; ct < 4; ++ct) {
      const int col = nt*64 + ct*16 + lr;
      const float bv = bfc[col];
      #pragma unroll
      for (int q = 0; q < 4; ++q) {
        const int row = w*16 + g*4 + q;
        out[((size_t)mt*64 + row)*256 + col] = fmaxf(acc[ct][q] + bv, 0.f);
      }
    }
  }
}

extern "C" void kernel_launch(void* const* d_in, const int* in_sizes, int n_in,
                              void* d_out, int out_size, void* d_ws, size_t ws_size,
                              hipStream_t stream) {
  const float* X      = (const float*)d_in[0];
  const float* W_ih_f = (const float*)d_in[1];
  const float* W_hh_f = (const float*)d_in[2];
  const float* b_ih_f = (const float*)d_in[3];
  const float* b_hh_f = (const float*)d_in[4];
  const float* W_ih_b = (const float*)d_in[5];
  const float* W_hh_b = (const float*)d_in[6];
  const float* b_ih_b = (const float*)d_in[7];
  const float* b_hh_b = (const float*)d_in[8];
  const float* W_fc   = (const float*)d_in[9];
  const float* b_fc   = (const float*)d_in[10];

  // CT=256 keeps the gxc chunk (50MB) L3-resident.
  int CT = 256;
  while (CT > 8 && ((size_t)CT*196608 + 131072) > ws_size) CT >>= 1;
  _Float16* gxc = (_Float16*)d_ws;                     // [2][CT][4][512][3][8] f16
  float*    wsh = (float*)((char*)d_ws + (size_t)CT*196608);  // [2][64][256] f32

  _Float16* h16   = (_Float16*)d_out;                  // [1024][64][512] f16 (in-place)
  float*    out   = (float*)d_out;                     // [1024][64][256] f32
  float*    hidden= (float*)d_out + (size_t)1024*64*256;

  const int NC = 1024 / CT;
  for (int c = 0; c < NC; ++c) {
    k_gx<<<dim3(CT, 2), dim3(256), 0, stream>>>(X, W_ih_f, b_ih_f, b_hh_f,
                                                W_ih_b, b_ih_b, b_hh_b, gxc, CT, c*CT);
    k_rec<<<dim3(8), dim3(512), 0, stream>>>(W_hh_f, b_hh_f, W_hh_b, b_hh_b,
                                             gxc, wsh, h16, hidden, CT, c*CT);
  }
  k_fc<<<dim3(1024), dim3(256), 0, stream>>>(h16, W_fc, b_fc, out);
}